// Round 3
// baseline (356.142 us; speedup 1.0000x reference)
//
#include <hip/hip_runtime.h>
#include <math.h>

// Problem dims (fixed by setup_inputs): B=4, L=4096, D_MODEL=2048, HALF=32
#define M_ROWS 16384   // B*L
#define DM     2048
#define NJ     64      // 2*HALF (interleaved re/im)
#define L_SEQ  4096
#define KH     1024    // K per split-K half

typedef __bf16 bf16x8 __attribute__((ext_vector_type(8)));
typedef float  f32x4  __attribute__((ext_vector_type(4)));

// Workspace BYTE offsets. Total ~75 MB (ws is ~512 MB per fill evidence).
constexpr size_t OB_BBART = 0;                         // bf16 [NJ][DM]
constexpr size_t OB_CCT   = 256 * 1024;                // bf16 [DM][NJ]
constexpr size_t OB_BUT   = 512 * 1024;                // f32  [2][NJ][M_ROWS] (split-K partials)
constexpr size_t OB_XST   = 512 * 1024 + 8u * 1024 * 1024;   // bf16 [M_ROWS][NJ]
constexpr size_t OB_UBF   = OB_XST + 2u * 1024 * 1024;       // bf16 [M_ROWS][DM]

static __device__ __forceinline__ unsigned short f2bf(float f) {
  unsigned int u = __float_as_uint(f);
  u = (u + 0x7fffu + ((u >> 16) & 1u)) >> 16;   // RNE
  return (unsigned short)u;
}

// Register-only f32x8 -> bf16x8 (element casts; unions block SROA -> scratch).
static __device__ __forceinline__ bf16x8 cvt8(float4 a, float4 b) {
  bf16x8 r;
  r[0] = (__bf16)a.x; r[1] = (__bf16)a.y; r[2] = (__bf16)a.z; r[3] = (__bf16)a.w;
  r[4] = (__bf16)b.x; r[5] = (__bf16)b.y; r[6] = (__bf16)b.z; r[7] = (__bf16)b.w;
  return r;
}

// ---------------------------------------------------------------------------
__global__ void k_prep(const float* __restrict__ lam_ur, const float* __restrict__ lam_im,
                       const float* __restrict__ log_dt,
                       const float* __restrict__ Bre, const float* __restrict__ Bim,
                       const float* __restrict__ Cre, const float* __restrict__ Cim,
                       unsigned short* __restrict__ bbarT, unsigned short* __restrict__ ccT) {
  const int idx = blockIdx.x * 256 + threadIdx.x;  // 0..131071
  {  // bbarT: j = idx>>11, d = idx&2047
    const int j = idx >> 11, d = idx & 2047, n = j >> 1;
    float x = lam_ur[n];
    float sp = (x > 20.f) ? x : log1pf(expf(x));       // softplus
    float lre = -(sp + 1.0e-4f + 0.01f);
    float lim = lam_im[n];
    float dt = expf(log_dt[n]);
    float er = expf(lre * dt);
    float Are = er * cosf(lim * dt);
    float Aim = er * sinf(lim * dt);
    float den = lre * lre + lim * lim;
    float cre = ((Are - 1.f) * lre + Aim * lim) / den;  // (Lam_bar-1)/Lam
    float cim = (Aim * lre - (Are - 1.f) * lim) / den;
    float br = Bre[n * DM + d], bi = Bim[n * DM + d];
    float v = (j & 1) ? (cre * bi + cim * br) : (cre * br - cim * bi);
    bbarT[(size_t)j * DM + d] = f2bf(v);
  }
  {  // ccT: j = idx&63, d = idx>>6
    const int j = idx & 63, d = idx >> 6, n = j >> 1;
    float v = (j & 1) ? (-2.f * Cim[d * 32 + n]) : (2.f * Cre[d * 32 + n]);
    ccT[(size_t)d * NJ + j] = f2bf(v);
  }
}

// ---------------------------------------------------------------------------
// Bu GEMM, split-K=2: bu_t[ks][j][row] = sum_{k in half ks} u[row][k]*bbarT[j][k].
// Barrier-free, LDS-free, depth-4 named-register pipeline (16 KB/wave in
// flight). Wave owns 16 rows x 32 j; block = 32 rows x 64 j x K-half.
// jh==0 waves also emit u as bf16 (ubf) for k_out's epilogue.
__global__ __launch_bounds__(256) void k_bu(const float* __restrict__ u,
                                            const unsigned short* __restrict__ bbarT,
                                            float* __restrict__ bu_t,
                                            unsigned short* __restrict__ ubf) {
  const int t = threadIdx.x;
  const int wave = t >> 6, lane = t & 63;
  const int rs = wave & 1;      // row-strip within block
  const int jh = wave >> 1;     // j-half (32 j = 2 MFMA tiles)
  const int m0 = blockIdx.x * 32 + rs * 16;
  const int ks = blockIdx.y;    // K-half
  const int kb = ks * KH;
  const int l15 = lane & 15, kq8 = (lane >> 4) * 8;
  const float* up = u + (size_t)(m0 + l15) * DM + kb + kq8;
  const unsigned short* bp0 = bbarT + (size_t)(jh * 32 + l15) * DM + kb + kq8;
  const unsigned short* bp1 = bp0 + (size_t)16 * DM;
  unsigned short* wp = ubf + (size_t)(m0 + l15) * DM + kb + kq8;
  f32x4 acc0 = {0.f, 0.f, 0.f, 0.f}, acc1 = {0.f, 0.f, 0.f, 0.f};
  float4 v0_0, v1_0, v0_1, v1_1, v0_2, v1_2, v0_3, v1_3;
  bf16x8 b0_0, b1_0, b0_1, b1_1, b0_2, b1_2, b0_3, b1_3;
#define LOADS(S, K)                                  \
  do {                                               \
    v0_##S = *(const float4*)(up + (K));             \
    v1_##S = *(const float4*)(up + (K) + 4);         \
    b0_##S = *(const bf16x8*)(bp0 + (K));            \
    b1_##S = *(const bf16x8*)(bp1 + (K));            \
  } while (0)
#define CONSUME(S, K)                                                        \
  do {                                                                       \
    bf16x8 a = cvt8(v0_##S, v1_##S);                                         \
    if (jh == 0) *(bf16x8*)(wp + (K)) = a;                                   \
    acc0 = __builtin_amdgcn_mfma_f32_16x16x32_bf16(a, b0_##S, acc0, 0, 0, 0);\
    acc1 = __builtin_amdgcn_mfma_f32_16x16x32_bf16(a, b1_##S, acc1, 0, 0, 0);\
  } while (0)
  LOADS(0, 0); LOADS(1, 32); LOADS(2, 64); LOADS(3, 96);
  int k0 = 0;
#pragma unroll 1
  for (int it = 0; it < (KH / 128) - 1; ++it, k0 += 128) {
    CONSUME(0, k0);      LOADS(0, k0 + 128);
    CONSUME(1, k0 + 32); LOADS(1, k0 + 160);
    CONSUME(2, k0 + 64); LOADS(2, k0 + 192);
    CONSUME(3, k0 + 96); LOADS(3, k0 + 224);
  }
  CONSUME(0, k0); CONSUME(1, k0 + 32); CONSUME(2, k0 + 64); CONSUME(3, k0 + 96);
#undef LOADS
#undef CONSUME
  // C layout: col=lane&15 -> j, rows (lane>>4)*4+i contiguous -> float4 store.
  const int j0 = jh * 32 + l15;
  const int orow = m0 + (lane >> 4) * 4;
  float* bo = bu_t + (size_t)ks * NJ * M_ROWS;
  *(f32x4*)&bo[(size_t)j0 * M_ROWS + orow] = acc0;
  *(f32x4*)&bo[(size_t)(j0 + 16) * M_ROWS + orow] = acc1;
}

// ---------------------------------------------------------------------------
// Associative scan along L per (b, n): x_t = A*x_{t-1} + Bu_t (complex).
// Sums the two split-K partials on load; writes xs_t ROW-major [row][NJ].
__global__ __launch_bounds__(256) void k_scan(const float* __restrict__ bu_t,
                                              const float* __restrict__ lam_ur,
                                              const float* __restrict__ lam_im,
                                              const float* __restrict__ log_dt,
                                              unsigned short* __restrict__ xs_t) {
  __shared__ float sre[L_SEQ + 256], sim[L_SEQ + 256];  // padded: e' = e + (e>>4)
  __shared__ float2 P[256];
  const int n = blockIdx.x;  // 0..31
  const int b = blockIdx.y;  // 0..3
  const int t = threadIdx.x;
  float x = lam_ur[n];
  float sp = (x > 20.f) ? x : log1pf(expf(x));
  float lre = -(sp + 1.0e-4f + 0.01f);
  float lim = lam_im[n];
  float dt = expf(log_dt[n]);
  float er = expf(lre * dt);
  const float Are = er * cosf(lim * dt);
  const float Aim = er * sinf(lim * dt);
  const float* pr0 = bu_t + (size_t)(2 * n) * M_ROWS + (size_t)b * L_SEQ;
  const float* pi0 = bu_t + (size_t)(2 * n + 1) * M_ROWS + (size_t)b * L_SEQ;
  const float* pr1 = pr0 + (size_t)NJ * M_ROWS;
  const float* pi1 = pi0 + (size_t)NJ * M_ROWS;
#pragma unroll
  for (int i0 = 4 * t; i0 < L_SEQ; i0 += 1024) {
    float4 va = *(const float4*)(pr0 + i0);
    float4 vb = *(const float4*)(pr1 + i0);
    float4 wa = *(const float4*)(pi0 + i0);
    float4 wb = *(const float4*)(pi1 + i0);
    const float rr[4] = {va.x + vb.x, va.y + vb.y, va.z + vb.z, va.w + vb.w};
    const float ii[4] = {wa.x + wb.x, wa.y + wb.y, wa.z + wb.z, wa.w + wb.w};
#pragma unroll
    for (int q = 0; q < 4; ++q) {
      int e = i0 + q, ee = e + (e >> 4);
      sre[ee] = rr[q];
      sim[ee] = ii[q];
    }
  }
  __syncthreads();
  // Local inclusive scan of 16 consecutive elements (LDS base 17*t).
  float lre16[16], lim16[16];
  float xre = 0.f, xim = 0.f;
#pragma unroll
  for (int i = 0; i < 16; ++i) {
    float bre = sre[17 * t + i], bim = sim[17 * t + i];
    float nr = Are * xre - Aim * xim + bre;
    float ni = Are * xim + Aim * xre + bim;
    xre = nr; xim = ni;
    lre16[i] = nr; lim16[i] = ni;
  }
  // M = A^16 by repeated squaring.
  float Mre = Are, Mim = Aim;
#pragma unroll
  for (int k = 0; k < 4; ++k) {
    float nr = Mre * Mre - Mim * Mim;
    float ni = 2.f * Mre * Mim;
    Mre = nr; Mim = ni;
  }
  // Hillis-Steele inclusive scan of per-thread carries.
  float pre = xre, pim = xim;
  P[t] = make_float2(pre, pim);
  __syncthreads();
  float msre = Mre, msim = Mim;  // M^s
  for (int s = 1; s < 256; s <<= 1) {
    float2 prev = (t >= s) ? P[t - s] : make_float2(0.f, 0.f);
    __syncthreads();
    pre += msre * prev.x - msim * prev.y;
    pim += msre * prev.y + msim * prev.x;
    P[t] = make_float2(pre, pim);
    float nr = msre * msre - msim * msim;
    float ni = 2.f * msre * msim;
    msre = nr; msim = ni;
    __syncthreads();
  }
  float2 E = (t == 0) ? make_float2(0.f, 0.f) : P[t - 1];
  // x_i_final = local_i + A^{i+1} * E; write back to LDS for the store pass.
  float pwre = Are, pwim = Aim;
#pragma unroll
  for (int i = 0; i < 16; ++i) {
    sre[17 * t + i] = lre16[i] + pwre * E.x - pwim * E.y;
    sim[17 * t + i] = lim16[i] + pwre * E.y + pwim * E.x;
    float nr = pwre * Are - pwim * Aim;
    float ni = pwre * Aim + pwim * Are;
    pwre = nr; pwim = ni;
  }
  __syncthreads();
  // ROW-major store: one packed (re,im) uint per row, stride NJ/2 uints.
  unsigned int* xp = (unsigned int*)(xs_t + (size_t)b * L_SEQ * NJ + 2 * n);
  for (int i = t; i < L_SEQ; i += 256) {
    int p = i + (i >> 4);
    xp[(size_t)i * (NJ / 2)] = ((unsigned int)f2bf(sim[p]) << 16) | f2bf(sre[p]);
  }
}

// ---------------------------------------------------------------------------
// Output GEMM: y[row][d] = sum_j xs[row][j]*ccT[d][j] + D[d]*u[row][d].
// A-fragments direct from row-major xs_t; epilogue reads bf16 u (ubf, half
// the bytes of fp32 u) + LDS fp32 transpose for float4-coalesced y stores.
__global__ __launch_bounds__(256) void k_out(const unsigned short* __restrict__ xs_t,
                                             const unsigned short* __restrict__ ccT,
                                             const unsigned short* __restrict__ ubf,
                                             const float* __restrict__ Dv,
                                             float* __restrict__ y) {
  __shared__ __align__(16) float Es[64][132];                  // 33.8 KB
  const int t = threadIdx.x;
  const int wave = t >> 6, lane = t & 63;
  const int m0 = blockIdx.x * 64;
  const int d0 = blockIdx.y * 128;
  const int l15 = lane & 15, kq8 = (lane >> 4) * 8;
  const unsigned short* ap = xs_t + (size_t)(m0 + wave * 16 + l15) * NJ;
  bf16x8 a0 = *(const bf16x8*)(ap + kq8);
  bf16x8 a1 = *(const bf16x8*)(ap + 32 + kq8);
  f32x4 acc[8];
#pragma unroll
  for (int c = 0; c < 8; ++c) acc[c] = (f32x4){0.f, 0.f, 0.f, 0.f};
#pragma unroll
  for (int c = 0; c < 8; ++c) {
    const unsigned short* cp = ccT + (size_t)(d0 + c * 16 + l15) * NJ + kq8;
    bf16x8 b0 = *(const bf16x8*)cp;
    bf16x8 b1 = *(const bf16x8*)(cp + 32);
    acc[c] = __builtin_amdgcn_mfma_f32_16x16x32_bf16(a0, b0, acc[c], 0, 0, 0);
    acc[c] = __builtin_amdgcn_mfma_f32_16x16x32_bf16(a1, b1, acc[c], 0, 0, 0);
  }
#pragma unroll
  for (int c = 0; c < 8; ++c)
#pragma unroll
    for (int i = 0; i < 4; ++i)
      Es[wave * 16 + (lane >> 4) * 4 + i][c * 16 + l15] = acc[c][i];
  __syncthreads();
  // Coalesced epilogue: float4 y per lane; u read as bf16 (8B/lane).
#pragma unroll
  for (int p = 0; p < 8; ++p) {
    int idx = t + 256 * p;       // 0..2047
    int row = idx >> 5;          // 0..63
    int c4 = (idx & 31) * 4;     // 0..124
    f32x4 e = *(const f32x4*)&Es[row][c4];
    const size_t off = (size_t)(m0 + row) * DM + d0 + c4;
    ushort4 ub = *(const ushort4*)&ubf[off];
    float4 dd = *(const float4*)&Dv[d0 + c4];
    float4 o;
    o.x = e[0] + dd.x * __uint_as_float((unsigned int)ub.x << 16);
    o.y = e[1] + dd.y * __uint_as_float((unsigned int)ub.y << 16);
    o.z = e[2] + dd.z * __uint_as_float((unsigned int)ub.z << 16);
    o.w = e[3] + dd.w * __uint_as_float((unsigned int)ub.w << 16);
    *(float4*)&y[off] = o;
  }
}

// ---------------------------------------------------------------------------
extern "C" void kernel_launch(void* const* d_in, const int* in_sizes, int n_in,
                              void* d_out, int out_size, void* d_ws, size_t ws_size,
                              hipStream_t stream) {
  const float* u      = (const float*)d_in[0];
  const float* lam_ur = (const float*)d_in[1];
  const float* lam_im = (const float*)d_in[2];
  const float* B_re   = (const float*)d_in[3];
  const float* B_im   = (const float*)d_in[4];
  const float* C_re   = (const float*)d_in[5];
  const float* C_im   = (const float*)d_in[6];
  const float* Dv     = (const float*)d_in[7];
  const float* log_dt = (const float*)d_in[8];
  float* y = (float*)d_out;
  char* ws = (char*)d_ws;

  unsigned short* bbarT = (unsigned short*)(ws + OB_BBART);
  unsigned short* ccT   = (unsigned short*)(ws + OB_CCT);
  float*          bu_t  = (float*)(ws + OB_BUT);
  unsigned short* xs_t  = (unsigned short*)(ws + OB_XST);
  unsigned short* ubf   = (unsigned short*)(ws + OB_UBF);

  k_prep<<<512, 256, 0, stream>>>(lam_ur, lam_im, log_dt, B_re, B_im, C_re, C_im, bbarT, ccT);
  k_bu<<<dim3(M_ROWS / 32, 2), 256, 0, stream>>>(u, bbarT, bu_t, ubf);
  k_scan<<<dim3(32, 4), 256, 0, stream>>>(bu_t, lam_ur, lam_im, log_dt, xs_t);
  k_out<<<dim3(M_ROWS / 64, DM / 128), 256, 0, stream>>>(xs_t, ccT, ubf, Dv, y);
}

// Round 5
// 309.722 us; speedup vs baseline: 1.1499x; 1.1499x over previous
//
#include <hip/hip_runtime.h>
#include <math.h>

// Problem dims (fixed by setup_inputs): B=4, L=4096, D_MODEL=2048, HALF=32
#define M_ROWS 16384   // B*L
#define DM     2048
#define NJ     64      // 2*HALF (interleaved re/im)
#define L_SEQ  4096
#define KH     1024    // K per split-K half

typedef __bf16 bf16x8 __attribute__((ext_vector_type(8)));
typedef float  f32x4  __attribute__((ext_vector_type(4)));

// Workspace BYTE offsets. Total ~11 MB.
constexpr size_t OB_BBART = 0;                               // bf16 [NJ][DM]
constexpr size_t OB_CCT   = 256 * 1024;                      // bf16 [DM][NJ]
constexpr size_t OB_BUT   = 512 * 1024;                      // f32  [2][NJ][M_ROWS]
constexpr size_t OB_XST   = 512 * 1024 + 8u * 1024 * 1024;   // bf16 [M_ROWS][NJ]

#define AS1C(p) ((const __attribute__((address_space(1))) unsigned int*)(p))
#define AS3(p)  ((__attribute__((address_space(3))) unsigned int*)(p))

static __device__ __forceinline__ unsigned short f2bf(float f) {
  unsigned int u = __float_as_uint(f);
  u = (u + 0x7fffu + ((u >> 16) & 1u)) >> 16;   // RNE
  return (unsigned short)u;
}

// Register-only f32x8 -> bf16x8 (element casts; unions block SROA -> scratch).
static __device__ __forceinline__ bf16x8 cvt8(float4 a, float4 b) {
  bf16x8 r;
  r[0] = (__bf16)a.x; r[1] = (__bf16)a.y; r[2] = (__bf16)a.z; r[3] = (__bf16)a.w;
  r[4] = (__bf16)b.x; r[5] = (__bf16)b.y; r[6] = (__bf16)b.z; r[7] = (__bf16)b.w;
  return r;
}

// ---------------------------------------------------------------------------
__global__ void k_prep(const float* __restrict__ lam_ur, const float* __restrict__ lam_im,
                       const float* __restrict__ log_dt,
                       const float* __restrict__ Bre, const float* __restrict__ Bim,
                       const float* __restrict__ Cre, const float* __restrict__ Cim,
                       unsigned short* __restrict__ bbarT, unsigned short* __restrict__ ccT) {
  const int idx = blockIdx.x * 256 + threadIdx.x;  // 0..131071
  {  // bbarT: j = idx>>11, d = idx&2047
    const int j = idx >> 11, d = idx & 2047, n = j >> 1;
    float x = lam_ur[n];
    float sp = (x > 20.f) ? x : log1pf(expf(x));       // softplus
    float lre = -(sp + 1.0e-4f + 0.01f);
    float lim = lam_im[n];
    float dt = expf(log_dt[n]);
    float er = expf(lre * dt);
    float Are = er * cosf(lim * dt);
    float Aim = er * sinf(lim * dt);
    float den = lre * lre + lim * lim;
    float cre = ((Are - 1.f) * lre + Aim * lim) / den;  // (Lam_bar-1)/Lam
    float cim = (Aim * lre - (Are - 1.f) * lim) / den;
    float br = Bre[n * DM + d], bi = Bim[n * DM + d];
    float v = (j & 1) ? (cre * bi + cim * br) : (cre * br - cim * bi);
    bbarT[(size_t)j * DM + d] = f2bf(v);
  }
  {  // ccT: j = idx&63, d = idx>>6
    const int j = idx & 63, d = idx >> 6, n = j >> 1;
    float v = (j & 1) ? (-2.f * Cim[d * 32 + n]) : (2.f * Cre[d * 32 + n]);
    ccT[(size_t)d * NJ + j] = f2bf(v);
  }
}

// ---------------------------------------------------------------------------
// Bu GEMM, split-K=2: bu_t[ks][j][row] = sum_{k half} u[row][k]*bbarT[j][k].
// m97-style staged structure: u tile (32 rows x 128 K fp32, 16 KB) staged to
// LDS via global_load_lds width=16 (contiguous global reads), A-frags read
// from LDS with XOR swizzle (rule #21: linear LDS dest + inverse-swizzled
// global SOURCE + same swizzle on read). Block = 4 waves: wave owns 16 rows
// (rs) x 32 j (jh). bbarT (256 KB, L2-resident) loaded direct per chunk.
__global__ __launch_bounds__(256) void k_bu(const float* __restrict__ u,
                                            const unsigned short* __restrict__ bbarT,
                                            float* __restrict__ bu_t) {
  __shared__ __align__(16) float Ut[32 * 128];  // 16 KB; [row][slot] float4-slots
  const int t = threadIdx.x;
  const int wave = t >> 6, lane = t & 63;
  const int rs = wave & 1;      // row-strip (16 rows)
  const int jh = wave >> 1;     // j-half (32 j = 2 MFMA col-tiles)
  const int m0 = blockIdx.x * 32;
  const int ks = blockIdx.y;    // K-half
  const int l15 = lane & 15, kq8 = (lane >> 4) * 8;
  // Staging geometry: wave-uniform LDS base + lane*16 (HW rule). For issue p,
  // LDS byte o = p*4096 + wave*1024 + lane*16 -> row = p*8+wave*2+(lane>>5),
  // slot = lane&31. Source float4 index = slot ^ (row&7)  (inverse swizzle).
  const int srow = wave * 2 + (lane >> 5);
  const int sslot = lane & 31;
  const int r = rs * 16 + l15;                  // this lane's A row in tile
  const unsigned short* bp0 = bbarT + (size_t)(jh * 32 + l15) * DM + ks * KH + kq8;
  const unsigned short* bp1 = bp0 + (size_t)16 * DM;
  f32x4 acc0 = {0.f, 0.f, 0.f, 0.f}, acc1 = {0.f, 0.f, 0.f, 0.f};
#pragma unroll 1
  for (int step = 0; step < KH / 128; ++step) {
    const int k0 = ks * KH + step * 128;
#pragma unroll
    for (int p = 0; p < 4; ++p) {
      const int row = p * 8 + srow;
      const float* src = u + (size_t)(m0 + row) * DM + k0 + ((sslot ^ (row & 7)) << 2);
      __builtin_amdgcn_global_load_lds(AS1C(src), AS3(&Ut[p * 1024 + wave * 256]),
                                       16, 0, 0);
    }
    __syncthreads();   // vmcnt(0) drain: tile resident
#pragma unroll
    for (int c = 0; c < 4; ++c) {
      const int f4a = c * 8 + (kq8 >> 2);       // logical float4 index (this lane)
      float4 va = *(const float4*)&Ut[(r * 32 + (f4a ^ (r & 7))) * 4];
      float4 vb = *(const float4*)&Ut[(r * 32 + ((f4a + 1) ^ (r & 7))) * 4];
      bf16x8 a = cvt8(va, vb);
      bf16x8 b0 = *(const bf16x8*)(bp0 + step * 128 + c * 32);
      bf16x8 b1 = *(const bf16x8*)(bp1 + step * 128 + c * 32);
      acc0 = __builtin_amdgcn_mfma_f32_16x16x32_bf16(a, b0, acc0, 0, 0, 0);
      acc1 = __builtin_amdgcn_mfma_f32_16x16x32_bf16(a, b1, acc1, 0, 0, 0);
    }
    __syncthreads();   // all waves done reading before next stage overwrites
  }
  // C layout: col=lane&15 -> j, rows (lane>>4)*4+i contiguous -> float4 store.
  const int j0 = jh * 32 + l15;
  const int orow = m0 + rs * 16 + (lane >> 4) * 4;
  float* bo = bu_t + (size_t)ks * NJ * M_ROWS;
  *(f32x4*)&bo[(size_t)j0 * M_ROWS + orow] = acc0;
  *(f32x4*)&bo[(size_t)(j0 + 16) * M_ROWS + orow] = acc1;
}

// ---------------------------------------------------------------------------
// Associative scan along L per (b, n): x_t = A*x_{t-1} + Bu_t (complex).
// Sums the two split-K partials on load; writes xs_t ROW-major [row][NJ].
__global__ __launch_bounds__(256) void k_scan(const float* __restrict__ bu_t,
                                              const float* __restrict__ lam_ur,
                                              const float* __restrict__ lam_im,
                                              const float* __restrict__ log_dt,
                                              unsigned short* __restrict__ xs_t) {
  __shared__ float sre[L_SEQ + 256], sim[L_SEQ + 256];  // padded: e' = e + (e>>4)
  __shared__ float2 P[256];
  const int n = blockIdx.x;  // 0..31
  const int b = blockIdx.y;  // 0..3
  const int t = threadIdx.x;
  float x = lam_ur[n];
  float sp = (x > 20.f) ? x : log1pf(expf(x));
  float lre = -(sp + 1.0e-4f + 0.01f);
  float lim = lam_im[n];
  float dt = expf(log_dt[n]);
  float er = expf(lre * dt);
  const float Are = er * cosf(lim * dt);
  const float Aim = er * sinf(lim * dt);
  const float* pr0 = bu_t + (size_t)(2 * n) * M_ROWS + (size_t)b * L_SEQ;
  const float* pi0 = bu_t + (size_t)(2 * n + 1) * M_ROWS + (size_t)b * L_SEQ;
  const float* pr1 = pr0 + (size_t)NJ * M_ROWS;
  const float* pi1 = pi0 + (size_t)NJ * M_ROWS;
#pragma unroll
  for (int i0 = 4 * t; i0 < L_SEQ; i0 += 1024) {
    float4 va = *(const float4*)(pr0 + i0);
    float4 vb = *(const float4*)(pr1 + i0);
    float4 wa = *(const float4*)(pi0 + i0);
    float4 wb = *(const float4*)(pi1 + i0);
    const float rr[4] = {va.x + vb.x, va.y + vb.y, va.z + vb.z, va.w + vb.w};
    const float ii[4] = {wa.x + wb.x, wa.y + wb.y, wa.z + wb.z, wa.w + wb.w};
#pragma unroll
    for (int q = 0; q < 4; ++q) {
      int e = i0 + q, ee = e + (e >> 4);
      sre[ee] = rr[q];
      sim[ee] = ii[q];
    }
  }
  __syncthreads();
  // Local inclusive scan of 16 consecutive elements (LDS base 17*t).
  float lre16[16], lim16[16];
  float xre = 0.f, xim = 0.f;
#pragma unroll
  for (int i = 0; i < 16; ++i) {
    float bre = sre[17 * t + i], bim = sim[17 * t + i];
    float nr = Are * xre - Aim * xim + bre;
    float ni = Are * xim + Aim * xre + bim;
    xre = nr; xim = ni;
    lre16[i] = nr; lim16[i] = ni;
  }
  // M = A^16 by repeated squaring.
  float Mre = Are, Mim = Aim;
#pragma unroll
  for (int k = 0; k < 4; ++k) {
    float nr = Mre * Mre - Mim * Mim;
    float ni = 2.f * Mre * Mim;
    Mre = nr; Mim = ni;
  }
  // Hillis-Steele inclusive scan of per-thread carries.
  float pre = xre, pim = xim;
  P[t] = make_float2(pre, pim);
  __syncthreads();
  float msre = Mre, msim = Mim;  // M^s
  for (int s = 1; s < 256; s <<= 1) {
    float2 prev = (t >= s) ? P[t - s] : make_float2(0.f, 0.f);
    __syncthreads();
    pre += msre * prev.x - msim * prev.y;
    pim += msre * prev.y + msim * prev.x;
    P[t] = make_float2(pre, pim);
    float nr = msre * msre - msim * msim;
    float ni = 2.f * msre * msim;
    msre = nr; msim = ni;
    __syncthreads();
  }
  float2 E = (t == 0) ? make_float2(0.f, 0.f) : P[t - 1];
  // x_i_final = local_i + A^{i+1} * E; write back to LDS for the store pass.
  float pwre = Are, pwim = Aim;
#pragma unroll
  for (int i = 0; i < 16; ++i) {
    sre[17 * t + i] = lre16[i] + pwre * E.x - pwim * E.y;
    sim[17 * t + i] = lim16[i] + pwre * E.y + pwim * E.x;
    float nr = pwre * Are - pwim * Aim;
    float ni = pwre * Aim + pwim * Are;
    pwre = nr; pwim = ni;
  }
  __syncthreads();
  // ROW-major store: one packed (re,im) uint per row, stride NJ/2 uints.
  unsigned int* xp = (unsigned int*)(xs_t + (size_t)b * L_SEQ * NJ + 2 * n);
  for (int i = t; i < L_SEQ; i += 256) {
    int p = i + (i >> 4);
    xp[(size_t)i * (NJ / 2)] = ((unsigned int)f2bf(sim[p]) << 16) | f2bf(sre[p]);
  }
}

// ---------------------------------------------------------------------------
// Output GEMM: y[row][d] = sum_j xs[row][j]*ccT[d][j] + D[d]*u[row][d].
// A-fragments direct from row-major xs_t (L2-resident); epilogue via LDS
// fp32 transpose -> float4-coalesced u loads and y stores.
__global__ __launch_bounds__(256) void k_out(const unsigned short* __restrict__ xs_t,
                                             const unsigned short* __restrict__ ccT,
                                             const float* __restrict__ u,
                                             const float* __restrict__ Dv,
                                             float* __restrict__ y) {
  __shared__ __align__(16) float Es[64][132];                  // 33.8 KB
  const int t = threadIdx.x;
  const int wave = t >> 6, lane = t & 63;
  const int m0 = blockIdx.x * 64;
  const int d0 = blockIdx.y * 128;
  const int l15 = lane & 15, kq8 = (lane >> 4) * 8;
  const unsigned short* ap = xs_t + (size_t)(m0 + wave * 16 + l15) * NJ;
  bf16x8 a0 = *(const bf16x8*)(ap + kq8);
  bf16x8 a1 = *(const bf16x8*)(ap + 32 + kq8);
  f32x4 acc[8];
#pragma unroll
  for (int c = 0; c < 8; ++c) acc[c] = (f32x4){0.f, 0.f, 0.f, 0.f};
#pragma unroll
  for (int c = 0; c < 8; ++c) {
    const unsigned short* cp = ccT + (size_t)(d0 + c * 16 + l15) * NJ + kq8;
    bf16x8 b0 = *(const bf16x8*)cp;
    bf16x8 b1 = *(const bf16x8*)(cp + 32);
    acc[c] = __builtin_amdgcn_mfma_f32_16x16x32_bf16(a0, b0, acc[c], 0, 0, 0);
    acc[c] = __builtin_amdgcn_mfma_f32_16x16x32_bf16(a1, b1, acc[c], 0, 0, 0);
  }
#pragma unroll
  for (int c = 0; c < 8; ++c)
#pragma unroll
    for (int i = 0; i < 4; ++i)
      Es[wave * 16 + (lane >> 4) * 4 + i][c * 16 + l15] = acc[c][i];
  __syncthreads();
  // Coalesced epilogue: float4 per lane, 512B per 32 consecutive lanes.
#pragma unroll
  for (int p = 0; p < 8; ++p) {
    int idx = t + 256 * p;       // 0..2047
    int row = idx >> 5;          // 0..63
    int c4 = (idx & 31) * 4;     // 0..124
    f32x4 e = *(const f32x4*)&Es[row][c4];
    const size_t off = (size_t)(m0 + row) * DM + d0 + c4;
    float4 uu = *(const float4*)&u[off];
    float4 dd = *(const float4*)&Dv[d0 + c4];
    float4 o;
    o.x = e[0] + dd.x * uu.x;
    o.y = e[1] + dd.y * uu.y;
    o.z = e[2] + dd.z * uu.z;
    o.w = e[3] + dd.w * uu.w;
    *(float4*)&y[off] = o;
  }
}

// ---------------------------------------------------------------------------
extern "C" void kernel_launch(void* const* d_in, const int* in_sizes, int n_in,
                              void* d_out, int out_size, void* d_ws, size_t ws_size,
                              hipStream_t stream) {
  const float* u      = (const float*)d_in[0];
  const float* lam_ur = (const float*)d_in[1];
  const float* lam_im = (const float*)d_in[2];
  const float* B_re   = (const float*)d_in[3];
  const float* B_im   = (const float*)d_in[4];
  const float* C_re   = (const float*)d_in[5];
  const float* C_im   = (const float*)d_in[6];
  const float* Dv     = (const float*)d_in[7];
  const float* log_dt = (const float*)d_in[8];
  float* y = (float*)d_out;
  char* ws = (char*)d_ws;

  unsigned short* bbarT = (unsigned short*)(ws + OB_BBART);
  unsigned short* ccT   = (unsigned short*)(ws + OB_CCT);
  float*          bu_t  = (float*)(ws + OB_BUT);
  unsigned short* xs_t  = (unsigned short*)(ws + OB_XST);

  k_prep<<<512, 256, 0, stream>>>(lam_ur, lam_im, log_dt, B_re, B_im, C_re, C_im, bbarT, ccT);
  k_bu<<<dim3(M_ROWS / 32, 2), 256, 0, stream>>>(u, bbarT, bu_t);
  k_scan<<<dim3(32, 4), 256, 0, stream>>>(bu_t, lam_ur, lam_im, log_dt, xs_t);
  k_out<<<dim3(M_ROWS / 64, DM / 128), 256, 0, stream>>>(xs_t, ccT, u, Dv, y);
}